// Round 8
// baseline (2958.615 us; speedup 1.0000x reference)
//
#include <hip/hip_runtime.h>
#include <hip/hip_bf16.h>
#include <stdint.h>

#define D_MODEL 1024
#define D_FF    4096
#define N_ZONES 8
#define TOPK    3
#define RH      256
#define BATCH   16
#define SEQ     2048
#define NPAIR   (BATCH * TOPK)

typedef __bf16 bf16;
typedef __bf16 bf16x8 __attribute__((ext_vector_type(8)));
typedef __bf16 bf16x4 __attribute__((ext_vector_type(4)));
typedef float  f32x4  __attribute__((ext_vector_type(4)));

// ---------------- helpers ----------------

__device__ __forceinline__ void gload16(const void* g, void* l) {
  __builtin_amdgcn_global_load_lds((const __attribute__((address_space(1))) void*)g,
                                   (__attribute__((address_space(3))) void*)l,
                                   16, 0, 0);
}

__device__ __forceinline__ float gelu_tanh(float x) {
  float inner = 0.7978845608028654f * (x + 0.044715f * x * x * x);
  float t = __expf(2.0f * inner);
  float th = 1.0f - 2.0f / (t + 1.0f);
  return 0.5f * x * (1.0f + th);
}

__device__ __forceinline__ void xcd_remap(int& bx, int& by, int& bz) {
  int lin = blockIdx.x + gridDim.x * (blockIdx.y + gridDim.y * blockIdx.z);
  int nwg = gridDim.x * gridDim.y * gridDim.z;
  int ns  = (lin & 7) * (nwg >> 3) + (lin >> 3);
  bx = ns % gridDim.x; int rest = ns / gridDim.x;
  by = rest % gridDim.y; bz = rest / gridDim.y;
}

// ---------------- pooling ----------------

__global__ void pool_partial_kernel(const float* __restrict__ x, float* __restrict__ partial) {
  int sc = blockIdx.x;
  int b  = blockIdx.y;
  int tid = threadIdx.x;
  const float* xp = x + ((size_t)b * SEQ + (size_t)sc * 256) * D_MODEL;
  for (int i = 0; i < D_MODEL / 256; ++i) {
    int d = tid + i * 256;
    float s = 0.f;
    for (int ss = 0; ss < 256; ++ss) s += xp[(size_t)ss * D_MODEL + d];
    partial[((size_t)sc * BATCH + b) * D_MODEL + d] = s;
  }
}

__global__ void pool_final_kernel(const float* __restrict__ partial, float* __restrict__ pooled) {
  int b = blockIdx.x;
  int tid = threadIdx.x;
  for (int i = 0; i < D_MODEL / 256; ++i) {
    int d = tid + i * 256;
    float s = 0.f;
    for (int sc = 0; sc < 8; ++sc) s += partial[((size_t)sc * BATCH + b) * D_MODEL + d];
    pooled[b * D_MODEL + d] = s * (1.0f / SEQ);
  }
}

// ---------------- router ----------------

__global__ void router_kernel(const float* __restrict__ pooled,
                              const float* __restrict__ W1, const float* __restrict__ b1,
                              const float* __restrict__ W2, const float* __restrict__ b2,
                              int* __restrict__ route_e, float* __restrict__ route_w) {
  __shared__ float pld[D_MODEL];
  __shared__ float hls[RH];
  __shared__ float lg[N_ZONES];
  const int b = blockIdx.x;
  const int j = threadIdx.x;

  for (int i = 0; i < D_MODEL / RH; ++i) pld[j + i * RH] = pooled[b * D_MODEL + j + i * RH];
  __syncthreads();

  float acc = b1[j];
#pragma unroll 8
  for (int k = 0; k < D_MODEL; ++k) acc += pld[k] * W1[k * RH + j];
  hls[j] = tanhf(acc);
  __syncthreads();

  if (j < N_ZONES) {
    float s = b2[j];
    for (int t = 0; t < RH; ++t) s += hls[t] * W2[t * N_ZONES + j];
    lg[j] = s;
  }
  __syncthreads();

  if (j == 0) {
    float m = lg[0];
    for (int e = 1; e < N_ZONES; ++e) m = fmaxf(m, lg[e]);
    float p[N_ZONES]; float sum = 0.f;
    for (int e = 0; e < N_ZONES; ++e) { p[e] = expf(lg[e] - m); sum += p[e]; }
    int used[N_ZONES] = {0};
    int idx[TOPK]; float tv[TOPK]; float tsum = 0.f;
    for (int r = 0; r < TOPK; ++r) {
      int best = 0; float bv = -1.f;
      for (int e = 0; e < N_ZONES; ++e)
        if (!used[e] && p[e] > bv) { bv = p[e]; best = e; }
      used[best] = 1; idx[r] = best; tv[r] = bv / sum; tsum += bv / sum;
    }
    for (int r = 0; r < TOPK; ++r) {
      route_e[b * TOPK + r] = idx[r];
      route_w[b * TOPK + r] = tv[r] / tsum;
    }
  }
}

__global__ void sort_pairs_kernel(const int* __restrict__ route_e, int* __restrict__ perm) {
  if (threadIdx.x == 0 && blockIdx.x == 0) {
    int p = 0;
    for (int e = 0; e < N_ZONES; ++e)
      for (int i = 0; i < NPAIR; ++i)
        if (route_e[i] == e) perm[p++] = i;
  }
}

// ---------------- conversions (convert + out-init fused) ----------------

__global__ void convert_x_kernel(const float* __restrict__ x, bf16* __restrict__ xb,
                                 float* __restrict__ out) {
  size_t i = ((size_t)blockIdx.x * blockDim.x + threadIdx.x) * 8;
  const float4* p = (const float4*)(x + i);
  float4 v0 = p[0], v1 = p[1];
  bf16x8 o;
  o[0] = (bf16)v0.x; o[1] = (bf16)v0.y; o[2] = (bf16)v0.z; o[3] = (bf16)v0.w;
  o[4] = (bf16)v1.x; o[5] = (bf16)v1.y; o[6] = (bf16)v1.z; o[7] = (bf16)v1.w;
  *(bf16x8*)(xb + i) = o;
  float4* q = (float4*)(out + i);
  q[0] = v0; q[1] = v1;                 // out pre-init to x (gemm2 atomic-adds on top)
}

__global__ void transpose_kernel(const float* __restrict__ src, bf16* __restrict__ dst, int R, int C) {
  __shared__ float tile[64][65];
  int e = blockIdx.z;
  const float* s = src + (size_t)e * R * C;
  bf16* d = dst + (size_t)e * R * C;
  int r0 = blockIdx.y * 64, c0 = blockIdx.x * 64;
  int tc = threadIdx.x & 63, tr4 = threadIdx.x >> 6;
  for (int i = 0; i < 16; ++i) {
    int r = i * 4 + tr4;
    tile[r][tc] = s[(size_t)(r0 + r) * C + (c0 + tc)];
  }
  __syncthreads();
  for (int i = 0; i < 16; ++i) {
    int cc = i * 4 + tr4;
    d[(size_t)(c0 + cc) * R + (r0 + tc)] = (bf16)tile[tc][cc];
  }
}

// =====================================================================
// 256x256 GEMM core, single-barrier 4-phase schedule (derived waits).
// LDS: As/Bs = [2 buf][2 ks][256 rows][32 k] bf16 = 64KB each -> 128KB, 1 block/CU.
// 8 waves (2m x 4n), wave 128x64, acc[8][4] = acc[mh*4+mi][ni].
// Phase p in {P0..P3} of tile t (buf=t&1):
//   P0: RD(A ks0 mh0, B ks0); STG pair(A0,B0 of t+1 -> buf^1); BAR; lgkm0; 16 MFMA(ks0,mh0)
//   P1: RD(A ks0 mh1);        vmcnt(4);                        BAR; lgkm0; 16 MFMA(ks0,mh1)
//   P2: RD(A ks1 mh0, B ks1); STG pair(A1,B1 of t+1);          BAR; lgkm0; 16 MFMA(ks1,mh0)
//   P3: RD(A ks1 mh1);        vmcnt(4);                        BAR; lgkm0; 16 MFMA(ks1,mh1)
// Wait proof: stages (4 loads) at P0/P2 only. vmcnt(4)@P1(t) retires P2(t-1)'s pair
// (read at P2/P3(t), barrier@P1 makes it cross-wave). vmcnt(4)@P3(t) retires P0(t)'s...
// precisely: outstanding alternates {old4}+4 -> 8 -> vmcnt(4) retires the older pair,
// always exactly covering the pair read 4 phases after its stage. WAR: stage into buf^1
// at P0(t) vs tile t-1's reads of same region (P1(t-1)): separated by barriers P1-P3.
// MFMA operand swap: mfma(fB[ni], fA[mi], acc) -> lane value j at N = ni*16+fq*4+j,
// M = mi*16+fr  => 4 consecutive N per lane => packed 8B epilogue stores.
// Swizzle (conflict-0, r5-r7): src col ^= ((lane&3)^((lane>>3)&3))*8; read col ^= (fq^((fr>>1)&3))*8.
// =====================================================================

#define STGA(buf_, ks_, src_, ld_, kcb_)                                       \
  { const bf16* _s = (src_) + (size_t)(w * 16 + srow) * (ld_) + (kcb_) + (ks_) * 32 + swz; \
    bf16* _l = &As[((buf_) * 2 + (ks_)) * 8192] + w * 512;                     \
    gload16(_s, _l);                                                           \
    gload16(_s + (size_t)128 * (ld_), _l + 4096); }

#define STGB(buf_, ks_, src_, ld_, kcb_)                                       \
  { const bf16* _s = (src_) + (size_t)(w * 16 + srow) * (ld_) + (kcb_) + (ks_) * 32 + swz; \
    bf16* _l = &Bs[((buf_) * 2 + (ks_)) * 8192] + w * 512;                     \
    gload16(_s, _l);                                                           \
    gload16(_s + (size_t)128 * (ld_), _l + 4096); }

#define RDA(dst_, buf_, ks_, mh_)                                              \
  { const bf16* _p = &As[((buf_) * 2 + (ks_)) * 8192] + (size_t)(wm * 128 + (mh_) * 64 + fr) * 32 + swr; \
    _Pragma("unroll")                                                          \
    for (int i = 0; i < 4; ++i) dst_[i] = *(const bf16x8*)(_p + i * 512); }

#define RDB(dst_, buf_, ks_)                                                   \
  { const bf16* _p = &Bs[((buf_) * 2 + (ks_)) * 8192] + (size_t)(wn * 64 + fr) * 32 + swr; \
    _Pragma("unroll")                                                          \
    for (int i = 0; i < 4; ++i) dst_[i] = *(const bf16x8*)(_p + i * 512); }

#define BARX()                                                                 \
    __builtin_amdgcn_sched_barrier(0);                                         \
    __builtin_amdgcn_s_barrier();                                              \
    __builtin_amdgcn_sched_barrier(0);

#define VM4()  asm volatile("s_waitcnt vmcnt(4)" ::: "memory");

#define LGK0()                                                                 \
    asm volatile("s_waitcnt lgkmcnt(0)" ::: "memory");                         \
    __builtin_amdgcn_sched_barrier(0);

// swapped operands: first arg = B frag (output "row" = N), second = A frag ("col" = M)
#define MFMAQ(mh_, B_, A_)                                                     \
    __builtin_amdgcn_s_setprio(1);                                             \
    _Pragma("unroll")                                                          \
    for (int mi = 0; mi < 4; ++mi)                                             \
      _Pragma("unroll")                                                        \
      for (int ni = 0; ni < 4; ++ni)                                           \
        acc[(mh_) * 4 + mi][ni] = __builtin_amdgcn_mfma_f32_16x16x32_bf16(B_[ni], A_[mi], acc[(mh_) * 4 + mi][ni], 0, 0, 0); \
    __builtin_amdgcn_s_setprio(0);

#define GEMM_DECLS                                                             \
  const int tid = threadIdx.x;                                                 \
  const int lane = tid & 63;                                                   \
  const int w = tid >> 6;                                                      \
  const int wm = w >> 2, wn = w & 3;                                           \
  const int fr = lane & 15, fq = lane >> 4;                                    \
  const int swz = (((lane & 3) ^ ((lane >> 3) & 3)) * 8);                      \
  const int swr = ((fq ^ ((fr >> 1) & 3)) * 8);                                \
  const int srow = lane >> 2;                                                  \
  f32x4 acc[8][4] = {};                                                        \
  bf16x8 fA[4], fA2[4], fB[4];

// GEMM1: h = gelu(xb @ Wa[e]) * w_r
__launch_bounds__(512, 2)
__global__ void gemm1_kernel(const bf16* __restrict__ xb, const bf16* __restrict__ WaT,
                             const int* __restrict__ route_e, const float* __restrict__ route_w,
                             const int* __restrict__ perm,
                             bf16* __restrict__ hbuf, int s_base, int SR) {
  __shared__ bf16 As[2 * 2 * 8192];
  __shared__ bf16 Bs[2 * 2 * 8192];
  int bx, by, bz;
  xcd_remap(bx, by, bz);
  const int pair = perm[bz];
  const int b = pair / TOPK;
  const int e = route_e[pair];
  const float wr = route_w[pair];
  const int m0 = by * 256;
  const int n0 = bx * 256;
  GEMM_DECLS

  const bf16* Ag = xb  + ((size_t)b * SEQ + (size_t)(s_base + m0)) * D_MODEL;
  const bf16* Bg = WaT + ((size_t)e * D_FF + n0) * D_MODEL;

  // prologue: tile 0, pairs (A0,B0) then (A1,B1); retire first pair
  STGA(0, 0, Ag, D_MODEL, 0);
  STGB(0, 0, Bg, D_MODEL, 0);
  STGA(0, 1, Ag, D_MODEL, 0);
  STGB(0, 1, Bg, D_MODEL, 0);
  VM4(); BARX();

  const int NT = D_MODEL / 64;  // 16
  for (int t = 0; t < NT; ++t) {
    const int buf = t & 1, sbuf = buf ^ 1;
    const int tn = (t + 1 < NT) ? t + 1 : NT - 1;   // clamped dummy tail
    const int cb = tn * 64;
    // P0
    RDA(fA, buf, 0, 0); RDB(fB, buf, 0);
    STGA(sbuf, 0, Ag, D_MODEL, cb); STGB(sbuf, 0, Bg, D_MODEL, cb);
    BARX(); LGK0(); MFMAQ(0, fB, fA);
    // P1
    RDA(fA2, buf, 0, 1);
    VM4(); BARX(); LGK0(); MFMAQ(1, fB, fA2);
    // P2
    RDA(fA, buf, 1, 0); RDB(fB, buf, 1);
    STGA(sbuf, 1, Ag, D_MODEL, cb); STGB(sbuf, 1, Bg, D_MODEL, cb);
    BARX(); LGK0(); MFMAQ(0, fB, fA);
    // P3
    RDA(fA2, buf, 1, 1);
    VM4(); BARX(); LGK0(); MFMAQ(1, fB, fA2);
  }
  asm volatile("s_waitcnt vmcnt(0)" ::: "memory");

  // epilogue (swapped layout): lane value j at row M = ...+fr, col N = ni*16+fq*4+j
  // -> pack 4 consecutive N into one 8B store. 32 stores/thread.
  bf16* hout = hbuf + ((size_t)pair * SR + m0 + wm * 128) * D_FF + n0 + wn * 64;
#pragma unroll
  for (int MI = 0; MI < 8; ++MI) {
    const int row = (MI >> 2) * 64 + (MI & 3) * 16 + fr;
#pragma unroll
    for (int ni = 0; ni < 4; ++ni) {
      bf16x4 pk;
#pragma unroll
      for (int j = 0; j < 4; ++j) pk[j] = (bf16)(gelu_tanh(acc[MI][ni][j]) * wr);
      *(bf16x4*)(hout + (size_t)row * D_FF + ni * 16 + fq * 4) = pk;
    }
  }
}

// GEMM2: out += sum_r h[b,r] @ Wb[e_r]  (split-K=2, atomic f32; out pre-init to x)
__launch_bounds__(512, 2)
__global__ void gemm2_kernel(const bf16* __restrict__ hbuf, const bf16* __restrict__ WbT,
                             const int* __restrict__ route_e,
                             float* __restrict__ out, int s_base, int SR) {
  __shared__ bf16 As[2 * 2 * 8192];
  __shared__ bf16 Bs[2 * 2 * 8192];
  int bx, by, bz;
  xcd_remap(bx, by, bz);
  const int b = bz >> 1;
  const int ksl = bz & 1;
  const int m0 = by * 256;
  const int n0 = bx * 256;
  GEMM_DECLS

  const int e0 = route_e[b * TOPK + 0];
  const int e1 = route_e[b * TOPK + 1];
  const int e2 = route_e[b * TOPK + 2];
  const bf16* Ar[3] = {
    hbuf + ((size_t)(b * TOPK + 0) * SR + m0) * D_FF,
    hbuf + ((size_t)(b * TOPK + 1) * SR + m0) * D_FF,
    hbuf + ((size_t)(b * TOPK + 2) * SR + m0) * D_FF };
  const bf16* Br[3] = {
    WbT + ((size_t)e0 * D_MODEL + n0) * D_FF,
    WbT + ((size_t)e1 * D_MODEL + n0) * D_FF,
    WbT + ((size_t)e2 * D_MODEL + n0) * D_FF };

  const int k0 = ksl * 96, NTk = 96;

  {
    const int g = k0, rn = g >> 6, cb = (g & 63) * 64;
    const bf16* SA = Ar[rn]; const bf16* SB = Br[rn];
    STGA(0, 0, SA, D_FF, cb);
    STGB(0, 0, SB, D_FF, cb);
    STGA(0, 1, SA, D_FF, cb);
    STGB(0, 1, SB, D_FF, cb);
  }
  VM4(); BARX();

  for (int t = 0; t < NTk; ++t) {
    const int buf = t & 1, sbuf = buf ^ 1;
    const int gn = (t + 1 < NTk) ? k0 + t + 1 : k0 + NTk - 1;
    const int rn = gn >> 6;
    const int cb = (gn & 63) * 64;
    const bf16* SA = Ar[rn]; const bf16* SB = Br[rn];
    // P0
    RDA(fA, buf, 0, 0); RDB(fB, buf, 0);
    STGA(sbuf, 0, SA, D_FF, cb); STGB(sbuf, 0, SB, D_FF, cb);
    BARX(); LGK0(); MFMAQ(0, fB, fA);
    // P1
    RDA(fA2, buf, 0, 1);
    VM4(); BARX(); LGK0(); MFMAQ(1, fB, fA2);
    // P2
    RDA(fA, buf, 1, 0); RDB(fB, buf, 1);
    STGA(sbuf, 1, SA, D_FF, cb); STGB(sbuf, 1, SB, D_FF, cb);
    BARX(); LGK0(); MFMAQ(0, fB, fA);
    // P3
    RDA(fA2, buf, 1, 1);
    VM4(); BARX(); LGK0(); MFMAQ(1, fB, fA2);
  }
  asm volatile("s_waitcnt vmcnt(0)" ::: "memory");

  // epilogue (swapped layout): atomic add 4 consecutive cols per (MI, ni)
  const size_t ob = ((size_t)b * SEQ + (size_t)(s_base + m0 + wm * 128)) * D_MODEL + n0 + wn * 64;
#pragma unroll
  for (int MI = 0; MI < 8; ++MI) {
    const int row = (MI >> 2) * 64 + (MI & 3) * 16 + fr;
#pragma unroll
    for (int ni = 0; ni < 4; ++ni) {
#pragma unroll
      for (int j = 0; j < 4; ++j) {
        float* pp = out + ob + (size_t)row * D_MODEL + ni * 16 + fq * 4 + j;
        float vv = acc[MI][ni][j];
        asm volatile("global_atomic_add_f32 %0, %1, off" :: "v"(pp), "v"(vv) : "memory");
      }
    }
  }
}

// ---------------- sentinel ----------------

__global__ void fail_kernel(float* out, float v) {
  if (threadIdx.x < 64) out[threadIdx.x] = v;
}

// ---------------- host ----------------

extern "C" void kernel_launch(void* const* d_in, const int* in_sizes, int n_in,
                              void* d_out, int out_size, void* d_ws, size_t ws_size,
                              hipStream_t stream) {
  const float* x  = (const float*)d_in[0];
  const float* W1 = (const float*)d_in[1];
  const float* b1 = (const float*)d_in[2];
  const float* W2 = (const float*)d_in[3];
  const float* b2 = (const float*)d_in[4];
  const float* Wa = (const float*)d_in[5];
  const float* Wb = (const float*)d_in[6];
  float* out = (float*)d_out;

  char* ws = (char*)d_ws;
  size_t off = 0;
  auto walloc = [&](size_t bytes) -> void* {
    void* p = ws + off;
    off += (bytes + 255) & ~(size_t)255;
    return p;
  };

  float* partial = (float*)walloc((size_t)8 * BATCH * D_MODEL * 4);
  float* pooled  = (float*)walloc((size_t)BATCH * D_MODEL * 4);
  int*   route_e = (int*)walloc(NPAIR * 4);
  float* route_w = (float*)walloc(NPAIR * 4);
  int*   perm    = (int*)walloc(NPAIR * 4);
  bf16*  xb      = (bf16*)walloc((size_t)BATCH * SEQ * D_MODEL * 2);
  bf16*  WaT     = (bf16*)walloc((size_t)N_ZONES * D_MODEL * D_FF * 2);
  bf16*  WbT     = (bf16*)walloc((size_t)N_ZONES * D_MODEL * D_FF * 2);
  size_t fixed = off;

  int SR = 0;
  const int cands[2] = {512, 256};
  for (int ci = 0; ci < 2; ++ci) {
    size_t need = fixed + (size_t)NPAIR * cands[ci] * D_FF * 2 + 1024;
    if (need <= ws_size) { SR = cands[ci]; break; }
  }
  if (SR == 0) {
    fail_kernel<<<1, 64, 0, stream>>>(out, 1.0e6f + (float)(ws_size >> 20));
    return;
  }
  bf16* hbuf = (bf16*)walloc((size_t)NPAIR * SR * D_FF * 2);

  pool_partial_kernel<<<dim3(8, BATCH), 256, 0, stream>>>(x, partial);
  pool_final_kernel<<<BATCH, 256, 0, stream>>>(partial, pooled);
  router_kernel<<<BATCH, RH, 0, stream>>>(pooled, W1, b1, W2, b2, route_e, route_w);
  sort_pairs_kernel<<<1, 64, 0, stream>>>(route_e, perm);

  convert_x_kernel<<<(BATCH * SEQ * D_MODEL) / (256 * 8), 256, 0, stream>>>(x, xb, out);
  transpose_kernel<<<dim3(D_FF / 64, D_MODEL / 64, N_ZONES), 256, 0, stream>>>(Wa, WaT, D_MODEL, D_FF);
  transpose_kernel<<<dim3(D_MODEL / 64, D_FF / 64, N_ZONES), 256, 0, stream>>>(Wb, WbT, D_FF, D_MODEL);

  const int NS = SEQ / SR;
  for (int sl = 0; sl < NS; ++sl) {
    gemm1_kernel<<<dim3(D_FF / 256, SR / 256, NPAIR), 512, 0, stream>>>(
        xb, WaT, route_e, route_w, perm, hbuf, sl * SR, SR);
    gemm2_kernel<<<dim3(D_MODEL / 256, SR / 256, BATCH * 2), 512, 0, stream>>>(
        hbuf, WbT, route_e, out, sl * SR, SR);
  }
}

// Round 9
// 2295.281 us; speedup vs baseline: 1.2890x; 1.2890x over previous
//
#include <hip/hip_runtime.h>
#include <hip/hip_bf16.h>
#include <stdint.h>

#define D_MODEL 1024
#define D_FF    4096
#define N_ZONES 8
#define TOPK    3
#define RH      256
#define BATCH   16
#define SEQ     2048
#define NPAIR   (BATCH * TOPK)

typedef __bf16 bf16;
typedef __bf16 bf16x8 __attribute__((ext_vector_type(8)));
typedef __bf16 bf16x4 __attribute__((ext_vector_type(4)));
typedef float  f32x4  __attribute__((ext_vector_type(4)));

// ---------------- helpers ----------------

__device__ __forceinline__ void gload16(const void* g, void* l) {
  __builtin_amdgcn_global_load_lds((const __attribute__((address_space(1))) void*)g,
                                   (__attribute__((address_space(3))) void*)l,
                                   16, 0, 0);
}

__device__ __forceinline__ float gelu_tanh(float x) {
  float inner = 0.7978845608028654f * (x + 0.044715f * x * x * x);
  float t = __expf(2.0f * inner);
  float th = 1.0f - 2.0f / (t + 1.0f);
  return 0.5f * x * (1.0f + th);
}

__device__ __forceinline__ void xcd_remap(int& bx, int& by, int& bz) {
  int lin = blockIdx.x + gridDim.x * (blockIdx.y + gridDim.y * blockIdx.z);
  int nwg = gridDim.x * gridDim.y * gridDim.z;
  int ns  = (lin & 7) * (nwg >> 3) + (lin >> 3);
  bx = ns % gridDim.x; int rest = ns / gridDim.x;
  by = rest % gridDim.y; bz = rest / gridDim.y;
}

// ---------------- pooling ----------------

__global__ void pool_partial_kernel(const float* __restrict__ x, float* __restrict__ partial) {
  int sc = blockIdx.x;
  int b  = blockIdx.y;
  int tid = threadIdx.x;
  const float* xp = x + ((size_t)b * SEQ + (size_t)sc * 256) * D_MODEL;
  for (int i = 0; i < D_MODEL / 256; ++i) {
    int d = tid + i * 256;
    float s = 0.f;
    for (int ss = 0; ss < 256; ++ss) s += xp[(size_t)ss * D_MODEL + d];
    partial[((size_t)sc * BATCH + b) * D_MODEL + d] = s;
  }
}

__global__ void pool_final_kernel(const float* __restrict__ partial, float* __restrict__ pooled) {
  int b = blockIdx.x;
  int tid = threadIdx.x;
  for (int i = 0; i < D_MODEL / 256; ++i) {
    int d = tid + i * 256;
    float s = 0.f;
    for (int sc = 0; sc < 8; ++sc) s += partial[((size_t)sc * BATCH + b) * D_MODEL + d];
    pooled[b * D_MODEL + d] = s * (1.0f / SEQ);
  }
}

// ---------------- router ----------------

__global__ void router_kernel(const float* __restrict__ pooled,
                              const float* __restrict__ W1, const float* __restrict__ b1,
                              const float* __restrict__ W2, const float* __restrict__ b2,
                              int* __restrict__ route_e, float* __restrict__ route_w) {
  __shared__ float pld[D_MODEL];
  __shared__ float hls[RH];
  __shared__ float lg[N_ZONES];
  const int b = blockIdx.x;
  const int j = threadIdx.x;

  for (int i = 0; i < D_MODEL / RH; ++i) pld[j + i * RH] = pooled[b * D_MODEL + j + i * RH];
  __syncthreads();

  float acc = b1[j];
#pragma unroll 8
  for (int k = 0; k < D_MODEL; ++k) acc += pld[k] * W1[k * RH + j];
  hls[j] = tanhf(acc);
  __syncthreads();

  if (j < N_ZONES) {
    float s = b2[j];
    for (int t = 0; t < RH; ++t) s += hls[t] * W2[t * N_ZONES + j];
    lg[j] = s;
  }
  __syncthreads();

  if (j == 0) {
    float m = lg[0];
    for (int e = 1; e < N_ZONES; ++e) m = fmaxf(m, lg[e]);
    float p[N_ZONES]; float sum = 0.f;
    for (int e = 0; e < N_ZONES; ++e) { p[e] = expf(lg[e] - m); sum += p[e]; }
    int used[N_ZONES] = {0};
    int idx[TOPK]; float tv[TOPK]; float tsum = 0.f;
    for (int r = 0; r < TOPK; ++r) {
      int best = 0; float bv = -1.f;
      for (int e = 0; e < N_ZONES; ++e)
        if (!used[e] && p[e] > bv) { bv = p[e]; best = e; }
      used[best] = 1; idx[r] = best; tv[r] = bv / sum; tsum += bv / sum;
    }
    for (int r = 0; r < TOPK; ++r) {
      route_e[b * TOPK + r] = idx[r];
      route_w[b * TOPK + r] = tv[r] / tsum;
    }
  }
}

__global__ void sort_pairs_kernel(const int* __restrict__ route_e, int* __restrict__ perm) {
  if (threadIdx.x == 0 && blockIdx.x == 0) {
    int p = 0;
    for (int e = 0; e < N_ZONES; ++e)
      for (int i = 0; i < NPAIR; ++i)
        if (route_e[i] == e) perm[p++] = i;
  }
}

// ---------------- conversions (convert + out-init fused) ----------------

__global__ void convert_x_kernel(const float* __restrict__ x, bf16* __restrict__ xb,
                                 float* __restrict__ out) {
  size_t i = ((size_t)blockIdx.x * blockDim.x + threadIdx.x) * 8;
  const float4* p = (const float4*)(x + i);
  float4 v0 = p[0], v1 = p[1];
  bf16x8 o;
  o[0] = (bf16)v0.x; o[1] = (bf16)v0.y; o[2] = (bf16)v0.z; o[3] = (bf16)v0.w;
  o[4] = (bf16)v1.x; o[5] = (bf16)v1.y; o[6] = (bf16)v1.z; o[7] = (bf16)v1.w;
  *(bf16x8*)(xb + i) = o;
  float4* q = (float4*)(out + i);
  q[0] = v0; q[1] = v1;                 // out pre-init to x (gemm2 atomic-adds on top)
}

__global__ void transpose_kernel(const float* __restrict__ src, bf16* __restrict__ dst, int R, int C) {
  __shared__ float tile[64][65];
  int e = blockIdx.z;
  const float* s = src + (size_t)e * R * C;
  bf16* d = dst + (size_t)e * R * C;
  int r0 = blockIdx.y * 64, c0 = blockIdx.x * 64;
  int tc = threadIdx.x & 63, tr4 = threadIdx.x >> 6;
  for (int i = 0; i < 16; ++i) {
    int r = i * 4 + tr4;
    tile[r][tc] = s[(size_t)(r0 + r) * C + (c0 + tc)];
  }
  __syncthreads();
  for (int i = 0; i < 16; ++i) {
    int cc = i * 4 + tr4;
    d[(size_t)(c0 + cc) * R + (r0 + tc)] = (bf16)tile[tc][cc];
  }
}

// ---------------- shared per-kernel decls ----------------

#define GEMM_DECLS                                                             \
  const int tid = threadIdx.x;                                                 \
  const int lane = tid & 63;                                                   \
  const int w = tid >> 6;                                                      \
  const int wm = w >> 2, wn = w & 3;                                           \
  const int fr = lane & 15, fq = lane >> 4;                                    \
  const int swz = (((lane & 3) ^ ((lane >> 3) & 3)) * 8);                      \
  const int swr = ((fq ^ ((fr >> 1) & 3)) * 8);                                \
  const int srow = lane >> 2;

// =====================================================================
// GEMM1 (r5-proven fat-phase ring-2): 256x256, BK=64 (2 ksteps of 32).
// LDS As/Bs = [2 buf][2 ks][256x32] bf16 = 64KB each -> 128KB, 1 block/CU.
// Phase (t,ks): vmcnt(4); barrier; 12 ds_read (8 A + 4 B); stage next tile's
// matching ks (4 gloads); lgkmcnt(0); 32 MFMA (swapped operands).
// vmcnt(4): 8 outstanding at wait; retiring older 4 = exactly the half read now.
// Swizzle pair (conflict-0 proven): src col ^= ((lane&3)^((lane>>3)&3))*8,
// read col ^= (fq^((fr>>1)&3))*8.
// MFMA swap: mfma(fB[ni], fA[mi]) -> value j at M-row = mi*16+fr,
// N-col = ni*16+fq*4+j  => dense 8B-packed epilogue stores.
// =====================================================================

#define G1_PSTAGE4(buf_, ks_, kcb_)                                            \
  { const bf16* _sa = Ag + (size_t)(w * 16 + srow) * D_MODEL + (kcb_) + swz;   \
    bf16* _la = &As[((buf_) * 2 + (ks_)) * 8192] + w * 512;                    \
    gload16(_sa, _la);                                                         \
    gload16(_sa + (size_t)128 * D_MODEL, _la + 4096);                          \
    const bf16* _sb = Bg + (size_t)(w * 16 + srow) * D_MODEL + (kcb_) + swz;   \
    bf16* _lb = &Bs[((buf_) * 2 + (ks_)) * 8192] + w * 512;                    \
    gload16(_sb, _lb);                                                         \
    gload16(_sb + (size_t)128 * D_MODEL, _lb + 4096); }

#define G1_DSRD12(buf_, ks_)                                                   \
  { const bf16* Ah = &As[((buf_) * 2 + (ks_)) * 8192] + (size_t)(wm * 128 + fr) * 32 + swr; \
    _Pragma("unroll")                                                          \
    for (int i = 0; i < 8; ++i) fA[i] = *(const bf16x8*)(Ah + i * 512);        \
    const bf16* Bh = &Bs[((buf_) * 2 + (ks_)) * 8192] + (size_t)(wn * 64 + fr) * 32 + swr; \
    _Pragma("unroll")                                                          \
    for (int i = 0; i < 4; ++i) fB[i] = *(const bf16x8*)(Bh + i * 512); }

#define G1_FPHASE(rbuf_, rks_, sbuf_, sks_, kcb_)                              \
  { asm volatile("s_waitcnt vmcnt(4)" ::: "memory");                           \
    __builtin_amdgcn_s_barrier();                                              \
    __builtin_amdgcn_sched_barrier(0);                                         \
    G1_DSRD12(rbuf_, rks_);                                                    \
    G1_PSTAGE4(sbuf_, sks_, kcb_);                                             \
    asm volatile("s_waitcnt lgkmcnt(0)" ::: "memory");                         \
    __builtin_amdgcn_sched_barrier(0);                                         \
    __builtin_amdgcn_s_setprio(1);                                             \
    _Pragma("unroll")                                                          \
    for (int mi = 0; mi < 8; ++mi)                                             \
      _Pragma("unroll")                                                        \
      for (int ni = 0; ni < 4; ++ni)                                           \
        acc[mi][ni] = __builtin_amdgcn_mfma_f32_16x16x32_bf16(fB[ni], fA[mi], acc[mi][ni], 0, 0, 0); \
    __builtin_amdgcn_s_setprio(0); }

__launch_bounds__(512, 2)
__global__ void gemm1_kernel(const bf16* __restrict__ xb, const bf16* __restrict__ WaT,
                             const int* __restrict__ route_e, const float* __restrict__ route_w,
                             const int* __restrict__ perm,
                             bf16* __restrict__ hbuf, int s_base, int SR) {
  __shared__ bf16 As[2 * 2 * 8192];
  __shared__ bf16 Bs[2 * 2 * 8192];
  int bx, by, bz;
  xcd_remap(bx, by, bz);
  const int pair = perm[bz];          // expert-sorted: XCD chunk shares WaT panels
  const int b = pair / TOPK;
  const int e = route_e[pair];
  const float wr = route_w[pair];
  const int m0 = by * 256;
  const int n0 = bx * 256;
  GEMM_DECLS
  f32x4 acc[8][4] = {};
  bf16x8 fA[8], fB[4];

  const bf16* Ag = xb  + ((size_t)b * SEQ + (size_t)(s_base + m0)) * D_MODEL;
  const bf16* Bg = WaT + ((size_t)e * D_FF + n0) * D_MODEL;

  // prologue: tile 0, both ksteps -> buf 0 (8 loads outstanding)
  G1_PSTAGE4(0, 0, 0);
  G1_PSTAGE4(0, 1, 32);

  const int NT = D_MODEL / 64;  // 16
  int buf = 0;
  for (int t = 0; t < NT; ++t) {
    const int tn = (t + 1 < NT) ? t + 1 : NT - 1;   // clamped dummy tail
    const int cb = tn * 64;
    G1_FPHASE(buf, 0, buf ^ 1, 0, cb);
    G1_FPHASE(buf, 1, buf ^ 1, 1, cb + 32);
    buf ^= 1;
  }
  asm volatile("s_waitcnt vmcnt(0)" ::: "memory");

  // epilogue (swapped layout): row M = mi*16+fr, col N = ni*16+fq*4+j -> 8B packed
  bf16* hout = hbuf + ((size_t)pair * SR + m0 + wm * 128) * D_FF + n0 + wn * 64;
#pragma unroll
  for (int mi = 0; mi < 8; ++mi) {
    const int row = mi * 16 + fr;
#pragma unroll
    for (int ni = 0; ni < 4; ++ni) {
      bf16x4 pk;
#pragma unroll
      for (int j = 0; j < 4; ++j) pk[j] = (bf16)(gelu_tanh(acc[mi][ni][j]) * wr);
      *(bf16x4*)(hout + (size_t)row * D_FF + ni * 16 + fq * 4) = pk;
    }
  }
}

// =====================================================================
// GEMM2 (r6-proven): 256x256, 4 phases/tile, 2 barriers/phase, split-K=2,
// atomic f32 epilogue with row-contiguous lanes (WRITE_SIZE ~32MB proven).
// =====================================================================

#define G2_STGA(buf_, ks_, src_, kcb_)                                         \
  { const bf16* _s = (src_) + (size_t)(w * 16 + srow) * D_FF + (kcb_) + (ks_) * 32 + swz; \
    bf16* _l = &As[((buf_) * 2 + (ks_)) * 8192] + w * 512;                     \
    gload16(_s, _l);                                                           \
    gload16(_s + (size_t)128 * D_FF, _l + 4096); }

#define G2_STGB(buf_, ks_, src_, kcb_)                                         \
  { const bf16* _s = (src_) + (size_t)(w * 16 + srow) * D_FF + (kcb_) + (ks_) * 32 + swz; \
    bf16* _l = &Bs[((buf_) * 2 + (ks_)) * 8192] + w * 512;                     \
    gload16(_s, _l);                                                           \
    gload16(_s + (size_t)128 * D_FF, _l + 4096); }

#define G2_RDA(dst_, buf_, ks_, mh_)                                           \
  { const bf16* _p = &As[((buf_) * 2 + (ks_)) * 8192] + (size_t)(wm * 128 + (mh_) * 64 + fr) * 32 + swr; \
    _Pragma("unroll")                                                          \
    for (int i = 0; i < 4; ++i) dst_[i] = *(const bf16x8*)(_p + i * 512); }

#define G2_RDB(dst_, buf_, ks_)                                                \
  { const bf16* _p = &Bs[((buf_) * 2 + (ks_)) * 8192] + (size_t)(wn * 64 + fr) * 32 + swr; \
    _Pragma("unroll")                                                          \
    for (int i = 0; i < 4; ++i) dst_[i] = *(const bf16x8*)(_p + i * 512); }

#define G2_VMBAR()                                                             \
    asm volatile("s_waitcnt vmcnt(4)" ::: "memory");                           \
    __builtin_amdgcn_s_barrier();                                              \
    __builtin_amdgcn_sched_barrier(0);

#define G2_LGK0()                                                              \
    asm volatile("s_waitcnt lgkmcnt(0)" ::: "memory");                         \
    __builtin_amdgcn_sched_barrier(0);

#define G2_MFMAQ(mh_, A_, B_)                                                  \
    __builtin_amdgcn_s_setprio(1);                                             \
    _Pragma("unroll")                                                          \
    for (int mi = 0; mi < 4; ++mi)                                             \
      _Pragma("unroll")                                                        \
      for (int ni = 0; ni < 4; ++ni)                                           \
        acc[(mh_) * 4 + mi][ni] = __builtin_amdgcn_mfma_f32_16x16x32_bf16(A_[mi], B_[ni], acc[(mh_) * 4 + mi][ni], 0, 0, 0); \
    __builtin_amdgcn_s_setprio(0);                                             \
    __builtin_amdgcn_s_barrier();

__launch_bounds__(512, 2)
__global__ void gemm2_kernel(const bf16* __restrict__ hbuf, const bf16* __restrict__ WbT,
                             const int* __restrict__ route_e,
                             float* __restrict__ out, int s_base, int SR) {
  __shared__ bf16 As[2 * 2 * 8192];
  __shared__ bf16 Bs[2 * 2 * 8192];
  int bx, by, bz;
  xcd_remap(bx, by, bz);
  const int b = bz >> 1;
  const int ksl = bz & 1;          // K slice: tiles [ksl*96, ksl*96+96)
  const int m0 = by * 256;
  const int n0 = bx * 256;
  GEMM_DECLS
  f32x4 acc[8][4] = {};
  bf16x8 fA[4], fB0[4], fB1[4];

  const int e0 = route_e[b * TOPK + 0];
  const int e1 = route_e[b * TOPK + 1];
  const int e2 = route_e[b * TOPK + 2];
  const bf16* Ar[3] = {
    hbuf + ((size_t)(b * TOPK + 0) * SR + m0) * D_FF,
    hbuf + ((size_t)(b * TOPK + 1) * SR + m0) * D_FF,
    hbuf + ((size_t)(b * TOPK + 2) * SR + m0) * D_FF };
  const bf16* Br[3] = {
    WbT + ((size_t)e0 * D_MODEL + n0) * D_FF,
    WbT + ((size_t)e1 * D_MODEL + n0) * D_FF,
    WbT + ((size_t)e2 * D_MODEL + n0) * D_FF };

  const int k0 = ksl * 96, NTk = 96;

  {
    const int g = k0, rn = g >> 6, cb = (g & 63) * 64;
    const bf16* SA = Ar[rn]; const bf16* SB = Br[rn];
    G2_STGA(0, 0, SA, cb);
    G2_STGB(0, 0, SB, cb);
    G2_STGA(0, 1, SA, cb);
    G2_STGB(0, 1, SB, cb);
  }
  asm volatile("s_waitcnt vmcnt(4)" ::: "memory");
  __builtin_amdgcn_s_barrier();
  __builtin_amdgcn_sched_barrier(0);

  for (int t = 0; t < NTk; ++t) {
    const int buf = t & 1, sbuf = buf ^ 1;
    const int gn = (t + 1 < NTk) ? k0 + t + 1 : k0 + NTk - 1;
    const int rn = gn >> 6;
    const int cb = (gn & 63) * 64;
    const bf16* SA = Ar[rn]; const bf16* SB = Br[rn];
    // P0
    G2_RDA(fA, buf, 0, 0); G2_RDB(fB0, buf, 0);
    G2_STGA(sbuf, 0, SA, cb);
    G2_VMBAR(); G2_LGK0(); G2_MFMAQ(0, fA, fB0);
    // P1
    G2_RDA(fA, buf, 0, 1);
    G2_STGB(sbuf, 0, SB, cb);
    G2_VMBAR(); G2_LGK0(); G2_MFMAQ(1, fA, fB0);
    // P2
    G2_RDA(fA, buf, 1, 0); G2_RDB(fB1, buf, 1);
    G2_STGA(sbuf, 1, SA, cb);
    G2_VMBAR(); G2_LGK0(); G2_MFMAQ(0, fA, fB1);
    // P3
    G2_RDA(fA, buf, 1, 1);
    G2_STGB(sbuf, 1, SB, cb);
    G2_VMBAR(); G2_LGK0(); G2_MFMAQ(1, fA, fB1);
  }
  asm volatile("s_waitcnt vmcnt(0)" ::: "memory");

  // epilogue: atomic f32, lanes row-contiguous in N (proven low WRITE_SIZE)
  const size_t ob = ((size_t)b * SEQ + (size_t)(s_base + m0 + wm * 128)) * D_MODEL + n0 + wn * 64;
#pragma unroll
  for (int MI = 0; MI < 8; ++MI)
#pragma unroll
    for (int ni = 0; ni < 4; ++ni)
#pragma unroll
      for (int j = 0; j < 4; ++j) {
        int row = (MI >> 2) * 64 + (MI & 3) * 16 + fq * 4 + j;
        float* pp = out + ob + (size_t)row * D_MODEL + ni * 16 + fr;
        float vv = acc[MI][ni][j];
        asm volatile("global_atomic_add_f32 %0, %1, off" :: "v"(pp), "v"(vv) : "memory");
      }
}

// ---------------- sentinel ----------------

__global__ void fail_kernel(float* out, float v) {
  if (threadIdx.x < 64) out[threadIdx.x] = v;
}

// ---------------- host ----------------

extern "C" void kernel_launch(void* const* d_in, const int* in_sizes, int n_in,
                              void* d_out, int out_size, void* d_ws, size_t ws_size,
                              hipStream_t stream) {
  const float* x  = (const float*)d_in[0];
  const float* W1 = (const float*)d_in[1];
  const float* b1 = (const float*)d_in[2];
  const float* W2 = (const float*)d_in[3];
  const float* b2 = (const float*)d_in[4];
  const float* Wa = (const float*)d_in[5];
  const float* Wb = (const float*)d_in[6];
  float* out = (float*)d_out;

  char* ws = (char*)d_ws;
  size_t off = 0;
  auto walloc = [&](size_t bytes) -> void* {
    void* p = ws + off;
    off += (bytes + 255) & ~(size_t)255;
    return p;
  };

  float* partial = (float*)walloc((size_t)8 * BATCH * D_MODEL * 4);
  float* pooled  = (float*)walloc((size_t)BATCH * D_MODEL * 4);
  int*   route_e = (int*)walloc(NPAIR * 4);
  float* route_w = (float*)walloc(NPAIR * 4);
  int*   perm    = (int*)walloc(NPAIR * 4);
  bf16*  xb      = (bf16*)walloc((size_t)BATCH * SEQ * D_MODEL * 2);
  bf16*  WaT     = (bf16*)walloc((size_t)N_ZONES * D_MODEL * D_FF * 2);
  bf16*  WbT     = (bf16*)walloc((size_t)N_ZONES * D_MODEL * D_FF * 2);
  size_t fixed = off;

  int SR = 0;
  const int cands[2] = {512, 256};
  for (int ci = 0; ci < 2; ++ci) {
    size_t need = fixed + (size_t)NPAIR * cands[ci] * D_FF * 2 + 1024;
    if (need <= ws_size) { SR = cands[ci]; break; }
  }
  if (SR == 0) {
    fail_kernel<<<1, 64, 0, stream>>>(out, 1.0e6f + (float)(ws_size >> 20));
    return;
  }
  bf16* hbuf = (bf16*)walloc((size_t)NPAIR * SR * D_FF * 2);

  pool_partial_kernel<<<dim3(8, BATCH), 256, 0, stream>>>(x, partial);
  pool_final_kernel<<<BATCH, 256, 0, stream>>>(partial, pooled);
  router_kernel<<<BATCH, RH, 0, stream>>>(pooled, W1, b1, W2, b2, route_e, route_w);
  sort_pairs_kernel<<<1, 64, 0, stream>>>(route_e, perm);

  convert_x_kernel<<<(BATCH * SEQ * D_MODEL) / (256 * 8), 256, 0, stream>>>(x, xb, out);
  transpose_kernel<<<dim3(D_FF / 64, D_MODEL / 64, N_ZONES), 256, 0, stream>>>(Wa, WaT, D_MODEL, D_FF);
  transpose_kernel<<<dim3(D_MODEL / 64, D_FF / 64, N_ZONES), 256, 0, stream>>>(Wb, WbT, D_FF, D_MODEL);

  const int NS = SEQ / SR;
  for (int sl = 0; sl < NS; ++sl) {
    gemm1_kernel<<<dim3(D_FF / 256, SR / 256, NPAIR), 512, 0, stream>>>(
        xb, WaT, route_e, route_w, perm, hbuf, sl * SR, SR);
    gemm2_kernel<<<dim3(D_MODEL / 256, SR / 256, BATCH * 2), 512, 0, stream>>>(
        hbuf, WbT, route_e, out, sl * SR, SR);
  }
}

// Round 10
// 2176.960 us; speedup vs baseline: 1.3591x; 1.0544x over previous
//
#include <hip/hip_runtime.h>
#include <hip/hip_bf16.h>
#include <stdint.h>

#define D_MODEL 1024
#define D_FF    4096
#define N_ZONES 8
#define TOPK    3
#define RH      256
#define BATCH   16
#define SEQ     2048
#define NPAIR   (BATCH * TOPK)

typedef __bf16 bf16;
typedef __bf16 bf16x8 __attribute__((ext_vector_type(8)));
typedef __bf16 bf16x4 __attribute__((ext_vector_type(4)));
typedef float  f32x4  __attribute__((ext_vector_type(4)));

// ---------------- helpers ----------------

__device__ __forceinline__ void gload16(const void* g, void* l) {
  __builtin_amdgcn_global_load_lds((const __attribute__((address_space(1))) void*)g,
                                   (__attribute__((address_space(3))) void*)l,
                                   16, 0, 0);
}

__device__ __forceinline__ float gelu_tanh(float x) {
  float inner = 0.7978845608028654f * (x + 0.044715f * x * x * x);
  float t = __expf(2.0f * inner);
  float th = 1.0f - 2.0f / (t + 1.0f);
  return 0.5f * x * (1.0f + th);
}

__device__ __forceinline__ void xcd_remap(int& bx, int& by, int& bz) {
  int lin = blockIdx.x + gridDim.x * (blockIdx.y + gridDim.y * blockIdx.z);
  int nwg = gridDim.x * gridDim.y * gridDim.z;
  int ns  = (lin & 7) * (nwg >> 3) + (lin >> 3);
  bx = ns % gridDim.x; int rest = ns / gridDim.x;
  by = rest % gridDim.y; bz = rest / gridDim.y;
}

// ---------------- pooling ----------------

__global__ void pool_partial_kernel(const float* __restrict__ x, float* __restrict__ partial) {
  int sc = blockIdx.x;
  int b  = blockIdx.y;
  int tid = threadIdx.x;
  const float* xp = x + ((size_t)b * SEQ + (size_t)sc * 256) * D_MODEL;
  for (int i = 0; i < D_MODEL / 256; ++i) {
    int d = tid + i * 256;
    float s = 0.f;
    for (int ss = 0; ss < 256; ++ss) s += xp[(size_t)ss * D_MODEL + d];
    partial[((size_t)sc * BATCH + b) * D_MODEL + d] = s;
  }
}

__global__ void pool_final_kernel(const float* __restrict__ partial, float* __restrict__ pooled) {
  int b = blockIdx.x;
  int tid = threadIdx.x;
  for (int i = 0; i < D_MODEL / 256; ++i) {
    int d = tid + i * 256;
    float s = 0.f;
    for (int sc = 0; sc < 8; ++sc) s += partial[((size_t)sc * BATCH + b) * D_MODEL + d];
    pooled[b * D_MODEL + d] = s * (1.0f / SEQ);
  }
}

// ---------------- router ----------------

__global__ void router_kernel(const float* __restrict__ pooled,
                              const float* __restrict__ W1, const float* __restrict__ b1,
                              const float* __restrict__ W2, const float* __restrict__ b2,
                              int* __restrict__ route_e, float* __restrict__ route_w) {
  __shared__ float pld[D_MODEL];
  __shared__ float hls[RH];
  __shared__ float lg[N_ZONES];
  const int b = blockIdx.x;
  const int j = threadIdx.x;

  for (int i = 0; i < D_MODEL / RH; ++i) pld[j + i * RH] = pooled[b * D_MODEL + j + i * RH];
  __syncthreads();

  float acc = b1[j];
#pragma unroll 8
  for (int k = 0; k < D_MODEL; ++k) acc += pld[k] * W1[k * RH + j];
  hls[j] = tanhf(acc);
  __syncthreads();

  if (j < N_ZONES) {
    float s = b2[j];
    for (int t = 0; t < RH; ++t) s += hls[t] * W2[t * N_ZONES + j];
    lg[j] = s;
  }
  __syncthreads();

  if (j == 0) {
    float m = lg[0];
    for (int e = 1; e < N_ZONES; ++e) m = fmaxf(m, lg[e]);
    float p[N_ZONES]; float sum = 0.f;
    for (int e = 0; e < N_ZONES; ++e) { p[e] = expf(lg[e] - m); sum += p[e]; }
    int used[N_ZONES] = {0};
    int idx[TOPK]; float tv[TOPK]; float tsum = 0.f;
    for (int r = 0; r < TOPK; ++r) {
      int best = 0; float bv = -1.f;
      for (int e = 0; e < N_ZONES; ++e)
        if (!used[e] && p[e] > bv) { bv = p[e]; best = e; }
      used[best] = 1; idx[r] = best; tv[r] = bv / sum; tsum += bv / sum;
    }
    for (int r = 0; r < TOPK; ++r) {
      route_e[b * TOPK + r] = idx[r];
      route_w[b * TOPK + r] = tv[r] / tsum;
    }
  }
}

__global__ void sort_pairs_kernel(const int* __restrict__ route_e, int* __restrict__ perm) {
  if (threadIdx.x == 0 && blockIdx.x == 0) {
    int p = 0;
    for (int e = 0; e < N_ZONES; ++e)
      for (int i = 0; i < NPAIR; ++i)
        if (route_e[i] == e) perm[p++] = i;
  }
}

// ---------------- conversions (convert + out-init fused) ----------------

__global__ void convert_x_kernel(const float* __restrict__ x, bf16* __restrict__ xb,
                                 float* __restrict__ out) {
  size_t i = ((size_t)blockIdx.x * blockDim.x + threadIdx.x) * 8;
  const float4* p = (const float4*)(x + i);
  float4 v0 = p[0], v1 = p[1];
  bf16x8 o;
  o[0] = (bf16)v0.x; o[1] = (bf16)v0.y; o[2] = (bf16)v0.z; o[3] = (bf16)v0.w;
  o[4] = (bf16)v1.x; o[5] = (bf16)v1.y; o[6] = (bf16)v1.z; o[7] = (bf16)v1.w;
  *(bf16x8*)(xb + i) = o;
  float4* q = (float4*)(out + i);
  q[0] = v0; q[1] = v1;                 // out pre-init to x (gemm2 atomic-adds on top)
}

__global__ void transpose_kernel(const float* __restrict__ src, bf16* __restrict__ dst, int R, int C) {
  __shared__ float tile[64][65];
  int e = blockIdx.z;
  const float* s = src + (size_t)e * R * C;
  bf16* d = dst + (size_t)e * R * C;
  int r0 = blockIdx.y * 64, c0 = blockIdx.x * 64;
  int tc = threadIdx.x & 63, tr4 = threadIdx.x >> 6;
  for (int i = 0; i < 16; ++i) {
    int r = i * 4 + tr4;
    tile[r][tc] = s[(size_t)(r0 + r) * C + (c0 + tc)];
  }
  __syncthreads();
  for (int i = 0; i < 16; ++i) {
    int cc = i * 4 + tr4;
    d[(size_t)(c0 + cc) * R + (r0 + tc)] = (bf16)tile[tc][cc];
  }
}

// ---------------- shared per-kernel decls ----------------

#define GEMM_DECLS                                                             \
  const int tid = threadIdx.x;                                                 \
  const int lane = tid & 63;                                                   \
  const int w = tid >> 6;                                                      \
  const int wm = w >> 2, wn = w & 3;                                           \
  const int fr = lane & 15, fq = lane >> 4;                                    \
  const int swz = (((lane & 3) ^ ((lane >> 3) & 3)) * 8);                      \
  const int swr = ((fq ^ ((fr >> 1) & 3)) * 8);                                \
  const int srow = lane >> 2;

// =====================================================================
// Fat-phase ring-2 core (proven in gemm1 since r5): 256x256, BK=64 (2 ksteps).
// LDS As/Bs = [2 buf][2 ks][256x32] bf16 = 64KB each -> 128KB, 1 block/CU.
// Phase (t,ks): vmcnt(4); barrier; 12 ds_read (8 A + 4 B); stage next tile's
// matching ks (4 gloads); lgkmcnt(0); 32 MFMA.
// vmcnt(4): 8 outstanding at wait; retiring older 4 = exactly the half read now.
// Swizzle pair (conflict-0 proven): src col ^= ((lane&3)^((lane>>3)&3))*8,
// read col ^= (fq^((fr>>1)&3))*8.
// =====================================================================

#define FP_STAGE4(buf_, ks_, SA_, SB_, ld_, kcb_)                              \
  { const bf16* _sa = (SA_) + (size_t)(w * 16 + srow) * (ld_) + (kcb_) + swz;  \
    bf16* _la = &As[((buf_) * 2 + (ks_)) * 8192] + w * 512;                    \
    gload16(_sa, _la);                                                         \
    gload16(_sa + (size_t)128 * (ld_), _la + 4096);                            \
    const bf16* _sb = (SB_) + (size_t)(w * 16 + srow) * (ld_) + (kcb_) + swz;  \
    bf16* _lb = &Bs[((buf_) * 2 + (ks_)) * 8192] + w * 512;                    \
    gload16(_sb, _lb);                                                         \
    gload16(_sb + (size_t)128 * (ld_), _lb + 4096); }

#define FP_DSRD12(buf_, ks_)                                                   \
  { const bf16* Ah = &As[((buf_) * 2 + (ks_)) * 8192] + (size_t)(wm * 128 + fr) * 32 + swr; \
    _Pragma("unroll")                                                          \
    for (int i = 0; i < 8; ++i) fA[i] = *(const bf16x8*)(Ah + i * 512);        \
    const bf16* Bh = &Bs[((buf_) * 2 + (ks_)) * 8192] + (size_t)(wn * 64 + fr) * 32 + swr; \
    _Pragma("unroll")                                                          \
    for (int i = 0; i < 4; ++i) fB[i] = *(const bf16x8*)(Bh + i * 512); }

// SWAP_: 1 = mfma(fB,fA) (cols packed by fq -> dense 8B stores), 0 = mfma(fA,fB)
// (rows by fq*4+j, cols by fr -> line-covering atomic layout).
#define FP_PHASE(rbuf_, rks_, sbuf_, sks_, SA_, SB_, ld_, kcb_, SWAP_)         \
  { asm volatile("s_waitcnt vmcnt(4)" ::: "memory");                           \
    __builtin_amdgcn_s_barrier();                                              \
    __builtin_amdgcn_sched_barrier(0);                                         \
    FP_DSRD12(rbuf_, rks_);                                                    \
    FP_STAGE4(sbuf_, sks_, SA_, SB_, ld_, kcb_);                               \
    asm volatile("s_waitcnt lgkmcnt(0)" ::: "memory");                         \
    __builtin_amdgcn_sched_barrier(0);                                         \
    __builtin_amdgcn_s_setprio(1);                                             \
    _Pragma("unroll")                                                          \
    for (int mi = 0; mi < 8; ++mi)                                             \
      _Pragma("unroll")                                                        \
      for (int ni = 0; ni < 4; ++ni)                                           \
        acc[mi][ni] = (SWAP_)                                                  \
          ? __builtin_amdgcn_mfma_f32_16x16x32_bf16(fB[ni], fA[mi], acc[mi][ni], 0, 0, 0) \
          : __builtin_amdgcn_mfma_f32_16x16x32_bf16(fA[mi], fB[ni], acc[mi][ni], 0, 0, 0); \
    __builtin_amdgcn_s_setprio(0); }

// GEMM1: h = gelu(xb @ Wa[e]) * w_r  (swapped operands -> dense packed epilogue)
__launch_bounds__(512, 2)
__global__ void gemm1_kernel(const bf16* __restrict__ xb, const bf16* __restrict__ WaT,
                             const int* __restrict__ route_e, const float* __restrict__ route_w,
                             const int* __restrict__ perm,
                             bf16* __restrict__ hbuf, int s_base, int SR) {
  __shared__ bf16 As[2 * 2 * 8192];
  __shared__ bf16 Bs[2 * 2 * 8192];
  int bx, by, bz;
  xcd_remap(bx, by, bz);
  const int pair = perm[bz];          // expert-sorted: XCD chunk shares WaT panels
  const int b = pair / TOPK;
  const int e = route_e[pair];
  const float wr = route_w[pair];
  const int m0 = by * 256;
  const int n0 = bx * 256;
  GEMM_DECLS
  f32x4 acc[8][4] = {};
  bf16x8 fA[8], fB[4];

  const bf16* Ag = xb  + ((size_t)b * SEQ + (size_t)(s_base + m0)) * D_MODEL;
  const bf16* Bg = WaT + ((size_t)e * D_FF + n0) * D_MODEL;

  FP_STAGE4(0, 0, Ag, Bg, D_MODEL, 0);
  FP_STAGE4(0, 1, Ag, Bg, D_MODEL, 32);

  const int NT = D_MODEL / 64;  // 16
  int buf = 0;
  for (int t = 0; t < NT; ++t) {
    const int tn = (t + 1 < NT) ? t + 1 : NT - 1;   // clamped dummy tail
    const int cb = tn * 64;
    FP_PHASE(buf, 0, buf ^ 1, 0, Ag, Bg, D_MODEL, cb,      1);
    FP_PHASE(buf, 1, buf ^ 1, 1, Ag, Bg, D_MODEL, cb + 32, 1);
    buf ^= 1;
  }
  asm volatile("s_waitcnt vmcnt(0)" ::: "memory");

  // epilogue (swapped layout): row M = mi*16+fr, col N = ni*16+fq*4+j -> 8B packed
  bf16* hout = hbuf + ((size_t)pair * SR + m0 + wm * 128) * D_FF + n0 + wn * 64;
#pragma unroll
  for (int mi = 0; mi < 8; ++mi) {
    const int row = mi * 16 + fr;
#pragma unroll
    for (int ni = 0; ni < 4; ++ni) {
      bf16x4 pk;
#pragma unroll
      for (int j = 0; j < 4; ++j) pk[j] = (bf16)(gelu_tanh(acc[mi][ni][j]) * wr);
      *(bf16x4*)(hout + (size_t)row * D_FF + ni * 16 + fq * 4) = pk;
    }
  }
}

// GEMM2: out += sum_r h[b,r] @ Wb[e_r]  (fat-phase, split-K=2, atomic f32 epilogue)
__launch_bounds__(512, 2)
__global__ void gemm2_kernel(const bf16* __restrict__ hbuf, const bf16* __restrict__ WbT,
                             const int* __restrict__ route_e,
                             float* __restrict__ out, int s_base, int SR) {
  __shared__ bf16 As[2 * 2 * 8192];
  __shared__ bf16 Bs[2 * 2 * 8192];
  int bx, by, bz;
  xcd_remap(bx, by, bz);
  const int b = bz >> 1;
  const int ksl = bz & 1;          // K slice: tiles [ksl*96, ksl*96+96)
  const int m0 = by * 256;
  const int n0 = bx * 256;
  GEMM_DECLS
  f32x4 acc[8][4] = {};
  bf16x8 fA[8], fB[4];

  const int e0 = route_e[b * TOPK + 0];
  const int e1 = route_e[b * TOPK + 1];
  const int e2 = route_e[b * TOPK + 2];
  const bf16* Ar[3] = {
    hbuf + ((size_t)(b * TOPK + 0) * SR + m0) * D_FF,
    hbuf + ((size_t)(b * TOPK + 1) * SR + m0) * D_FF,
    hbuf + ((size_t)(b * TOPK + 2) * SR + m0) * D_FF };
  const bf16* Br[3] = {
    WbT + ((size_t)e0 * D_MODEL + n0) * D_FF,
    WbT + ((size_t)e1 * D_MODEL + n0) * D_FF,
    WbT + ((size_t)e2 * D_MODEL + n0) * D_FF };

  const int k0 = ksl * 96, NTk = 96;

  {
    const int rn = k0 >> 6, cb = (k0 & 63) * 64;
    FP_STAGE4(0, 0, Ar[rn], Br[rn], D_FF, cb);
    FP_STAGE4(0, 1, Ar[rn], Br[rn], D_FF, cb + 32);
  }

  int buf = 0;
  for (int t = 0; t < NTk; ++t) {
    const int gn = (t + 1 < NTk) ? k0 + t + 1 : k0 + NTk - 1;
    const int rn = gn >> 6;
    const int cb = (gn & 63) * 64;
    const bf16* SA = Ar[rn]; const bf16* SB = Br[rn];
    FP_PHASE(buf, 0, buf ^ 1, 0, SA, SB, D_FF, cb,      0);
    FP_PHASE(buf, 1, buf ^ 1, 1, SA, SB, D_FF, cb + 32, 0);
    buf ^= 1;
  }
  asm volatile("s_waitcnt vmcnt(0)" ::: "memory");

  // epilogue (unswapped layout): row = mi*16+fq*4+j, col = ni*16+fr
  // -> 16 lanes hit 16 consecutive 4B cols = full 64B lines (proven low WRITE_SIZE)
  const size_t ob = ((size_t)b * SEQ + (size_t)(s_base + m0 + wm * 128)) * D_MODEL + n0 + wn * 64;
#pragma unroll
  for (int mi = 0; mi < 8; ++mi)
#pragma unroll
    for (int ni = 0; ni < 4; ++ni)
#pragma unroll
      for (int j = 0; j < 4; ++j) {
        int row = mi * 16 + fq * 4 + j;
        float* pp = out + ob + (size_t)row * D_MODEL + ni * 16 + fr;
        float vv = acc[mi][ni][j];
        asm volatile("global_atomic_add_f32 %0, %1, off" :: "v"(pp), "v"(vv) : "memory");
      }
}

// ---------------- sentinel ----------------

__global__ void fail_kernel(float* out, float v) {
  if (threadIdx.x < 64) out[threadIdx.x] = v;
}

// ---------------- host ----------------

extern "C" void kernel_launch(void* const* d_in, const int* in_sizes, int n_in,
                              void* d_out, int out_size, void* d_ws, size_t ws_size,
                              hipStream_t stream) {
  const float* x  = (const float*)d_in[0];
  const float* W1 = (const float*)d_in[1];
  const float* b1 = (const float*)d_in[2];
  const float* W2 = (const float*)d_in[3];
  const float* b2 = (const float*)d_in[4];
  const float* Wa = (const float*)d_in[5];
  const float* Wb = (const float*)d_in[6];
  float* out = (float*)d_out;

  char* ws = (char*)d_ws;
  size_t off = 0;
  auto walloc = [&](size_t bytes) -> void* {
    void* p = ws + off;
    off += (bytes + 255) & ~(size_t)255;
    return p;
  };

  float* partial = (float*)walloc((size_t)8 * BATCH * D_MODEL * 4);
  float* pooled  = (float*)walloc((size_t)BATCH * D_MODEL * 4);
  int*   route_e = (int*)walloc(NPAIR * 4);
  float* route_w = (float*)walloc(NPAIR * 4);
  int*   perm    = (int*)walloc(NPAIR * 4);
  bf16*  xb      = (bf16*)walloc((size_t)BATCH * SEQ * D_MODEL * 2);
  bf16*  WaT     = (bf16*)walloc((size_t)N_ZONES * D_MODEL * D_FF * 2);
  bf16*  WbT     = (bf16*)walloc((size_t)N_ZONES * D_MODEL * D_FF * 2);
  size_t fixed = off;

  int SR = 0;
  const int cands[2] = {512, 256};
  for (int ci = 0; ci < 2; ++ci) {
    size_t need = fixed + (size_t)NPAIR * cands[ci] * D_FF * 2 + 1024;
    if (need <= ws_size) { SR = cands[ci]; break; }
  }
  if (SR == 0) {
    fail_kernel<<<1, 64, 0, stream>>>(out, 1.0e6f + (float)(ws_size >> 20));
    return;
  }
  bf16* hbuf = (bf16*)walloc((size_t)NPAIR * SR * D_FF * 2);

  pool_partial_kernel<<<dim3(8, BATCH), 256, 0, stream>>>(x, partial);
  pool_final_kernel<<<BATCH, 256, 0, stream>>>(partial, pooled);
  router_kernel<<<BATCH, RH, 0, stream>>>(pooled, W1, b1, W2, b2, route_e, route_w);
  sort_pairs_kernel<<<1, 64, 0, stream>>>(route_e, perm);

  convert_x_kernel<<<(BATCH * SEQ * D_MODEL) / (256 * 8), 256, 0, stream>>>(x, xb, out);
  transpose_kernel<<<dim3(D_FF / 64, D_MODEL / 64, N_ZONES), 256, 0, stream>>>(Wa, WaT, D_MODEL, D_FF);
  transpose_kernel<<<dim3(D_MODEL / 64, D_FF / 64, N_ZONES), 256, 0, stream>>>(Wb, WbT, D_FF, D_MODEL);

  const int NS = SEQ / SR;
  for (int sl = 0; sl < NS; ++sl) {
    gemm1_kernel<<<dim3(D_FF / 256, SR / 256, NPAIR), 512, 0, stream>>>(
        xb, WaT, route_e, route_w, perm, hbuf, sl * SR, SR);
    gemm2_kernel<<<dim3(D_MODEL / 256, SR / 256, BATCH * 2), 512, 0, stream>>>(
        hbuf, WbT, route_e, out, sl * SR, SR);
  }
}

// Round 11
// 2176.432 us; speedup vs baseline: 1.3594x; 1.0002x over previous
//
#include <hip/hip_runtime.h>
#include <hip/hip_bf16.h>
#include <stdint.h>

#define D_MODEL 1024
#define D_FF    4096
#define N_ZONES 8
#define TOPK    3
#define RH      256
#define BATCH   16
#define SEQ     2048
#define NPAIR   (BATCH * TOPK)

typedef __bf16 bf16;
typedef __bf16 bf16x8 __attribute__((ext_vector_type(8)));
typedef __bf16 bf16x4 __attribute__((ext_vector_type(4)));
typedef float  f32x4  __attribute__((ext_vector_type(4)));

// ---------------- helpers ----------------

__device__ __forceinline__ void gload16(const void* g, void* l) {
  __builtin_amdgcn_global_load_lds((const __attribute__((address_space(1))) void*)g,
                                   (__attribute__((address_space(3))) void*)l,
                                   16, 0, 0);
}

__device__ __forceinline__ float gelu_tanh(float x) {
  float inner = 0.7978845608028654f * (x + 0.044715f * x * x * x);
  float t = __expf(2.0f * inner);
  float th = 1.0f - 2.0f / (t + 1.0f);
  return 0.5f * x * (1.0f + th);
}

__device__ __forceinline__ void xcd_remap(int& bx, int& by, int& bz) {
  int lin = blockIdx.x + gridDim.x * (blockIdx.y + gridDim.y * blockIdx.z);
  int nwg = gridDim.x * gridDim.y * gridDim.z;
  int ns  = (lin & 7) * (nwg >> 3) + (lin >> 3);
  bx = ns % gridDim.x; int rest = ns / gridDim.x;
  by = rest % gridDim.y; bz = rest / gridDim.y;
}

// ---------------- pooling ----------------

__global__ void pool_partial_kernel(const float* __restrict__ x, float* __restrict__ partial) {
  int sc = blockIdx.x;
  int b  = blockIdx.y;
  int tid = threadIdx.x;
  const float* xp = x + ((size_t)b * SEQ + (size_t)sc * 256) * D_MODEL;
  for (int i = 0; i < D_MODEL / 256; ++i) {
    int d = tid + i * 256;
    float s = 0.f;
    for (int ss = 0; ss < 256; ++ss) s += xp[(size_t)ss * D_MODEL + d];
    partial[((size_t)sc * BATCH + b) * D_MODEL + d] = s;
  }
}

__global__ void pool_final_kernel(const float* __restrict__ partial, float* __restrict__ pooled) {
  int b = blockIdx.x;
  int tid = threadIdx.x;
  for (int i = 0; i < D_MODEL / 256; ++i) {
    int d = tid + i * 256;
    float s = 0.f;
    for (int sc = 0; sc < 8; ++sc) s += partial[((size_t)sc * BATCH + b) * D_MODEL + d];
    pooled[b * D_MODEL + d] = s * (1.0f / SEQ);
  }
}

// ---------------- router ----------------

__global__ void router_kernel(const float* __restrict__ pooled,
                              const float* __restrict__ W1, const float* __restrict__ b1,
                              const float* __restrict__ W2, const float* __restrict__ b2,
                              int* __restrict__ route_e, float* __restrict__ route_w) {
  __shared__ float pld[D_MODEL];
  __shared__ float hls[RH];
  __shared__ float lg[N_ZONES];
  const int b = blockIdx.x;
  const int j = threadIdx.x;

  for (int i = 0; i < D_MODEL / RH; ++i) pld[j + i * RH] = pooled[b * D_MODEL + j + i * RH];
  __syncthreads();

  float acc = b1[j];
#pragma unroll 8
  for (int k = 0; k < D_MODEL; ++k) acc += pld[k] * W1[k * RH + j];
  hls[j] = tanhf(acc);
  __syncthreads();

  if (j < N_ZONES) {
    float s = b2[j];
    for (int t = 0; t < RH; ++t) s += hls[t] * W2[t * N_ZONES + j];
    lg[j] = s;
  }
  __syncthreads();

  if (j == 0) {
    float m = lg[0];
    for (int e = 1; e < N_ZONES; ++e) m = fmaxf(m, lg[e]);
    float p[N_ZONES]; float sum = 0.f;
    for (int e = 0; e < N_ZONES; ++e) { p[e] = expf(lg[e] - m); sum += p[e]; }
    int used[N_ZONES] = {0};
    int idx[TOPK]; float tv[TOPK]; float tsum = 0.f;
    for (int r = 0; r < TOPK; ++r) {
      int best = 0; float bv = -1.f;
      for (int e = 0; e < N_ZONES; ++e)
        if (!used[e] && p[e] > bv) { bv = p[e]; best = e; }
      used[best] = 1; idx[r] = best; tv[r] = bv / sum; tsum += bv / sum;
    }
    for (int r = 0; r < TOPK; ++r) {
      route_e[b * TOPK + r] = idx[r];
      route_w[b * TOPK + r] = tv[r] / tsum;
    }
  }
}

__global__ void sort_pairs_kernel(const int* __restrict__ route_e, int* __restrict__ perm) {
  if (threadIdx.x == 0 && blockIdx.x == 0) {
    int p = 0;
    for (int e = 0; e < N_ZONES; ++e)
      for (int i = 0; i < NPAIR; ++i)
        if (route_e[i] == e) perm[p++] = i;
  }
}

// ---------------- conversions (convert + out-init fused) ----------------

__global__ void convert_x_kernel(const float* __restrict__ x, bf16* __restrict__ xb,
                                 float* __restrict__ out) {
  size_t i = ((size_t)blockIdx.x * blockDim.x + threadIdx.x) * 8;
  const float4* p = (const float4*)(x + i);
  float4 v0 = p[0], v1 = p[1];
  bf16x8 o;
  o[0] = (bf16)v0.x; o[1] = (bf16)v0.y; o[2] = (bf16)v0.z; o[3] = (bf16)v0.w;
  o[4] = (bf16)v1.x; o[5] = (bf16)v1.y; o[6] = (bf16)v1.z; o[7] = (bf16)v1.w;
  *(bf16x8*)(xb + i) = o;
  float4* q = (float4*)(out + i);
  q[0] = v0; q[1] = v1;                 // out pre-init to x (gemm2 atomic-adds on top)
}

__global__ void transpose_kernel(const float* __restrict__ src, bf16* __restrict__ dst, int R, int C) {
  __shared__ float tile[64][65];
  int e = blockIdx.z;
  const float* s = src + (size_t)e * R * C;
  bf16* d = dst + (size_t)e * R * C;
  int r0 = blockIdx.y * 64, c0 = blockIdx.x * 64;
  int tc = threadIdx.x & 63, tr4 = threadIdx.x >> 6;
  for (int i = 0; i < 16; ++i) {
    int r = i * 4 + tr4;
    tile[r][tc] = s[(size_t)(r0 + r) * C + (c0 + tc)];
  }
  __syncthreads();
  for (int i = 0; i < 16; ++i) {
    int cc = i * 4 + tr4;
    d[(size_t)(c0 + cc) * R + (r0 + tc)] = (bf16)tile[tc][cc];
  }
}

// ---------------- shared per-kernel decls ----------------

#define GEMM_DECLS                                                             \
  const int tid = threadIdx.x;                                                 \
  const int lane = tid & 63;                                                   \
  const int w = tid >> 6;                                                      \
  const int wm = w >> 2, wn = w & 3;                                           \
  const int fr = lane & 15, fq = lane >> 4;                                    \
  const int swz = (((lane & 3) ^ ((lane >> 3) & 3)) * 8);                      \
  const int swr = ((fq ^ ((fr >> 1) & 3)) * 8);                                \
  const int srow = lane >> 2;

// =====================================================================
// Fat-phase ring-2 core: 256x256, BK=64 (2 ksteps). LDS As/Bs = [2 buf][2 ks]
// [256x32] bf16 = 64KB each -> 128KB, 2 blocks/CU... 1 block/CU LDS, 2 via 128KB? (131072 -> 1/CU at 160KB: 1; measured Occ ~21% = 2 blk/CU across pool.)
// Phase (t,ks): vmcnt(4); barrier; FREE ZONE {12 ds_read (B first), stage 4
// gloads, 32 MFMA} -- NO forced lgkmcnt(0): compiler emits counted lgkm waits
// so MFMA starts after ~5 reads instead of all 12 (m97/m141 lesson).
// Trailing sched_barrier(0) pins MFMAs inside the phase (rule #18).
// WAR without drain: every read is consumed by an in-phase MFMA (hw lgkm wait
// retires it before the wave reaches the next barrier); stages write buf^1 only.
// vmcnt(4): 8 outstanding at wait; retiring older 4 = exactly the half read now.
// Swizzle pair (conflict-0 proven): src col ^= ((lane&3)^((lane>>3)&3))*8,
// read col ^= (fq^((fr>>1)&3))*8.
// =====================================================================

#define FP_STAGE4(buf_, ks_, SA_, SB_, ld_, kcb_)                              \
  { const bf16* _sa = (SA_) + (size_t)(w * 16 + srow) * (ld_) + (kcb_) + swz;  \
    bf16* _la = &As[((buf_) * 2 + (ks_)) * 8192] + w * 512;                    \
    gload16(_sa, _la);                                                         \
    gload16(_sa + (size_t)128 * (ld_), _la + 4096);                            \
    const bf16* _sb = (SB_) + (size_t)(w * 16 + srow) * (ld_) + (kcb_) + swz;  \
    bf16* _lb = &Bs[((buf_) * 2 + (ks_)) * 8192] + w * 512;                    \
    gload16(_sb, _lb);                                                         \
    gload16(_sb + (size_t)128 * (ld_), _lb + 4096); }

#define FP_DSRD12(buf_, ks_)                                                   \
  { const bf16* Bh = &Bs[((buf_) * 2 + (ks_)) * 8192] + (size_t)(wn * 64 + fr) * 32 + swr; \
    _Pragma("unroll")                                                          \
    for (int i = 0; i < 4; ++i) fB[i] = *(const bf16x8*)(Bh + i * 512);        \
    const bf16* Ah = &As[((buf_) * 2 + (ks_)) * 8192] + (size_t)(wm * 128 + fr) * 32 + swr; \
    _Pragma("unroll")                                                          \
    for (int i = 0; i < 8; ++i) fA[i] = *(const bf16x8*)(Ah + i * 512); }

// SWAP_: 1 = mfma(fB,fA) (cols packed by fq -> dense 8B stores), 0 = mfma(fA,fB)
// (rows by fq*4+j, cols by fr -> line-covering atomic layout).
#define FP_PHASE(rbuf_, rks_, sbuf_, sks_, SA_, SB_, ld_, kcb_, SWAP_)         \
  { asm volatile("s_waitcnt vmcnt(4)" ::: "memory");                           \
    __builtin_amdgcn_s_barrier();                                              \
    __builtin_amdgcn_sched_barrier(0);                                         \
    FP_DSRD12(rbuf_, rks_);                                                    \
    FP_STAGE4(sbuf_, sks_, SA_, SB_, ld_, kcb_);                               \
    __builtin_amdgcn_s_setprio(1);                                             \
    _Pragma("unroll")                                                          \
    for (int mi = 0; mi < 8; ++mi)                                             \
      _Pragma("unroll")                                                        \
      for (int ni = 0; ni < 4; ++ni)                                           \
        acc[mi][ni] = (SWAP_)                                                  \
          ? __builtin_amdgcn_mfma_f32_16x16x32_bf16(fB[ni], fA[mi], acc[mi][ni], 0, 0, 0) \
          : __builtin_amdgcn_mfma_f32_16x16x32_bf16(fA[mi], fB[ni], acc[mi][ni], 0, 0, 0); \
    __builtin_amdgcn_s_setprio(0);                                             \
    __builtin_amdgcn_sched_barrier(0); }

// GEMM1: h = gelu(xb @ Wa[e]) * w_r  (swapped operands -> dense packed epilogue)
__launch_bounds__(512, 2)
__global__ void gemm1_kernel(const bf16* __restrict__ xb, const bf16* __restrict__ WaT,
                             const int* __restrict__ route_e, const float* __restrict__ route_w,
                             const int* __restrict__ perm,
                             bf16* __restrict__ hbuf, int s_base, int SR) {
  __shared__ bf16 As[2 * 2 * 8192];
  __shared__ bf16 Bs[2 * 2 * 8192];
  int bx, by, bz;
  xcd_remap(bx, by, bz);
  const int pair = perm[bz];          // expert-sorted: XCD chunk shares WaT panels
  const int b = pair / TOPK;
  const int e = route_e[pair];
  const float wr = route_w[pair];
  const int m0 = by * 256;
  const int n0 = bx * 256;
  GEMM_DECLS
  f32x4 acc[8][4] = {};
  bf16x8 fA[8], fB[4];

  const bf16* Ag = xb  + ((size_t)b * SEQ + (size_t)(s_base + m0)) * D_MODEL;
  const bf16* Bg = WaT + ((size_t)e * D_FF + n0) * D_MODEL;

  FP_STAGE4(0, 0, Ag, Bg, D_MODEL, 0);
  FP_STAGE4(0, 1, Ag, Bg, D_MODEL, 32);

  const int NT = D_MODEL / 64;  // 16
  int buf = 0;
  for (int t = 0; t < NT; ++t) {
    const int tn = (t + 1 < NT) ? t + 1 : NT - 1;   // clamped dummy tail
    const int cb = tn * 64;
    FP_PHASE(buf, 0, buf ^ 1, 0, Ag, Bg, D_MODEL, cb,      1);
    FP_PHASE(buf, 1, buf ^ 1, 1, Ag, Bg, D_MODEL, cb + 32, 1);
    buf ^= 1;
  }
  asm volatile("s_waitcnt vmcnt(0)" ::: "memory");

  // epilogue (swapped layout): row M = mi*16+fr, col N = ni*16+fq*4+j -> 8B packed
  bf16* hout = hbuf + ((size_t)pair * SR + m0 + wm * 128) * D_FF + n0 + wn * 64;
#pragma unroll
  for (int mi = 0; mi < 8; ++mi) {
    const int row = mi * 16 + fr;
#pragma unroll
    for (int ni = 0; ni < 4; ++ni) {
      bf16x4 pk;
#pragma unroll
      for (int j = 0; j < 4; ++j) pk[j] = (bf16)(gelu_tanh(acc[mi][ni][j]) * wr);
      *(bf16x4*)(hout + (size_t)row * D_FF + ni * 16 + fq * 4) = pk;
    }
  }
}

// GEMM2: out += sum_r h[b,r] @ Wb[e_r]  (fat-phase, split-K=2, atomic f32 epilogue)
__launch_bounds__(512, 2)
__global__ void gemm2_kernel(const bf16* __restrict__ hbuf, const bf16* __restrict__ WbT,
                             const int* __restrict__ route_e,
                             float* __restrict__ out, int s_base, int SR) {
  __shared__ bf16 As[2 * 2 * 8192];
  __shared__ bf16 Bs[2 * 2 * 8192];
  int bx, by, bz;
  xcd_remap(bx, by, bz);
  const int b = bz >> 1;
  const int ksl = bz & 1;          // K slice: tiles [ksl*96, ksl*96+96)
  const int m0 = by * 256;
  const int n0 = bx * 256;
  GEMM_DECLS
  f32x4 acc[8][4] = {};
  bf16x8 fA[8], fB[4];

  const int e0 = route_e[b * TOPK + 0];
  const int e1 = route_e[b * TOPK + 1];
  const int e2 = route_e[b * TOPK + 2];
  const bf16* Ar[3] = {
    hbuf + ((size_t)(b * TOPK + 0) * SR + m0) * D_FF,
    hbuf + ((size_t)(b * TOPK + 1) * SR + m0) * D_FF,
    hbuf + ((size_t)(b * TOPK + 2) * SR + m0) * D_FF };
  const bf16* Br[3] = {
    WbT + ((size_t)e0 * D_MODEL + n0) * D_FF,
    WbT + ((size_t)e1 * D_MODEL + n0) * D_FF,
    WbT + ((size_t)e2 * D_MODEL + n0) * D_FF };

  const int k0 = ksl * 96, NTk = 96;

  {
    const int rn = k0 >> 6, cb = (k0 & 63) * 64;
    FP_STAGE4(0, 0, Ar[rn], Br[rn], D_FF, cb);
    FP_STAGE4(0, 1, Ar[rn], Br[rn], D_FF, cb + 32);
  }

  int buf = 0;
  for (int t = 0; t < NTk; ++t) {
    const int gn = (t + 1 < NTk) ? k0 + t + 1 : k0 + NTk - 1;
    const int rn = gn >> 6;
    const int cb = (gn & 63) * 64;
    const bf16* SA = Ar[rn]; const bf16* SB = Br[rn];
    FP_PHASE(buf, 0, buf ^ 1, 0, SA, SB, D_FF, cb,      0);
    FP_PHASE(buf, 1, buf ^ 1, 1, SA, SB, D_FF, cb + 32, 0);
    buf ^= 1;
  }
  asm volatile("s_waitcnt vmcnt(0)" ::: "memory");

  // epilogue (unswapped layout): row = mi*16+fq*4+j, col = ni*16+fr
  // -> 16 lanes hit 16 consecutive 4B cols = full 64B lines (proven low WRITE_SIZE)
  const size_t ob = ((size_t)b * SEQ + (size_t)(s_base + m0 + wm * 128)) * D_MODEL + n0 + wn * 64;
#pragma unroll
  for (int mi = 0; mi < 8; ++mi)
#pragma unroll
    for (int ni = 0; ni < 4; ++ni)
#pragma unroll
      for (int j = 0; j < 4; ++j) {
        int row = mi * 16 + fq * 4 + j;
        float* pp = out + ob + (size_t)row * D_MODEL + ni * 16 + fr;
        float vv = acc[mi][ni][j];
        asm volatile("global_atomic_add_f32 %0, %1, off" :: "v"(pp), "v"(vv) : "memory");
      }
}

// ---------------- sentinel ----------------

__global__ void fail_kernel(float* out, float v) {
  if (threadIdx.x < 64) out[threadIdx.x] = v;
}

// ---------------- host ----------------

extern "C" void kernel_launch(void* const* d_in, const int* in_sizes, int n_in,
                              void* d_out, int out_size, void* d_ws, size_t ws_size,
                              hipStream_t stream) {
  const float* x  = (const float*)d_in[0];
  const float* W1 = (const float*)d_in[1];
  const float* b1 = (const float*)d_in[2];
  const float* W2 = (const float*)d_in[3];
  const float* b2 = (const float*)d_in[4];
  const float* Wa = (const float*)d_in[5];
  const float* Wb = (const float*)d_in[6];
  float* out = (float*)d_out;

  char* ws = (char*)d_ws;
  size_t off = 0;
  auto walloc = [&](size_t bytes) -> void* {
    void* p = ws + off;
    off += (bytes + 255) & ~(size_t)255;
    return p;
  };

  float* partial = (float*)walloc((size_t)8 * BATCH * D_MODEL * 4);
  float* pooled  = (float*)walloc((size_t)BATCH * D_MODEL * 4);
  int*   route_e = (int*)walloc(NPAIR * 4);
  float* route_w = (float*)walloc(NPAIR * 4);
  int*   perm    = (int*)walloc(NPAIR * 4);
  bf16*  xb      = (bf16*)walloc((size_t)BATCH * SEQ * D_MODEL * 2);
  bf16*  WaT     = (bf16*)walloc((size_t)N_ZONES * D_MODEL * D_FF * 2);
  bf16*  WbT     = (bf16*)walloc((size_t)N_ZONES * D_MODEL * D_FF * 2);
  size_t fixed = off;

  int SR = 0;
  const int cands[2] = {512, 256};
  for (int ci = 0; ci < 2; ++ci) {
    size_t need = fixed + (size_t)NPAIR * cands[ci] * D_FF * 2 + 1024;
    if (need <= ws_size) { SR = cands[ci]; break; }
  }
  if (SR == 0) {
    fail_kernel<<<1, 64, 0, stream>>>(out, 1.0e6f + (float)(ws_size >> 20));
    return;
  }
  bf16* hbuf = (bf16*)walloc((size_t)NPAIR * SR * D_FF * 2);

  pool_partial_kernel<<<dim3(8, BATCH), 256, 0, stream>>>(x, partial);
  pool_final_kernel<<<BATCH, 256, 0, stream>>>(partial, pooled);
  router_kernel<<<BATCH, RH, 0, stream>>>(pooled, W1, b1, W2, b2, route_e, route_w);
  sort_pairs_kernel<<<1, 64, 0, stream>>>(route_e, perm);

  convert_x_kernel<<<(BATCH * SEQ * D_MODEL) / (256 * 8), 256, 0, stream>>>(x, xb, out);
  transpose_kernel<<<dim3(D_FF / 64, D_MODEL / 64, N_ZONES), 256, 0, stream>>>(Wa, WaT, D_MODEL, D_FF);
  transpose_kernel<<<dim3(D_MODEL / 64, D_FF / 64, N_ZONES), 256, 0, stream>>>(Wb, WbT, D_FF, D_MODEL);

  const int NS = SEQ / SR;
  for (int sl = 0; sl < NS; ++sl) {
    gemm1_kernel<<<dim3(D_FF / 256, SR / 256, NPAIR), 512, 0, stream>>>(
        xb, WaT, route_e, route_w, perm, hbuf, sl * SR, SR);
    gemm2_kernel<<<dim3(D_MODEL / 256, SR / 256, BATCH * 2), 512, 0, stream>>>(
        hbuf, WbT, route_e, out, sl * SR, SR);
  }
}